// Round 5
// baseline (111.024 us; speedup 1.0000x reference)
//
#include <hip/hip_runtime.h>
#include <math.h>

#define BS    128
#define NE    512
#define F     6
#define NH    4
#define DPH   4
#define NEMBD 16

#if __has_builtin(__builtin_amdgcn_exp2f)
#define EXP2(x) __builtin_amdgcn_exp2f(x)
#else
#define EXP2(x) exp2f(x)
#endif

typedef float v2f __attribute__((ext_vector_type(2)));

// ---------------------------------------------------------------------------
// attention: 2048 blocks = (b, h, quarter), 256 threads (8 blocks/CU -> up to
// 32 waves/CU; VGPR=68 caps at 28 -- vs 16 last round, which left VALUBusy
// at 57%). Thread t: key-chunk c=t&15 (32 keys), rows quar*128 + 8g + 0..7
// (g=t>>4), processed as 4 float2-packed row pairs (targets v_pk_fma_f32).
// 16 b128 chunk addresses/wave = 2-way bank aliasing (measured free, m136).
// No-max softmax: masked entities have k=v=0 exactly -> e=exp2(0)=1 and zero
// V contribution; l corrected by subtracting (512-N). Verified rounds 1-4.
// 4-step octet+hex butterfly combines the 16 chunks; lanes c<8 write.
// ---------------------------------------------------------------------------
#define CH    16
#define CKEYS 32
#define CPAD  33    // float4 stride/chunk: chunks c, c+8 share banks (2-way, free)

__global__ __launch_bounds__(256) void attn_kernel(
    const float* __restrict__ inp, const float* __restrict__ mask,
    const float* __restrict__ Wq, const float* __restrict__ Wk,
    const float* __restrict__ Wv, float* __restrict__ att_out)
{
    const int blk  = blockIdx.x;
    const int b    = blk >> 4;
    const int h    = (blk >> 2) & 3;
    const int quar = blk & 3;
    const int t    = threadIdx.x;
    const int c    = t & 15;
    const int g    = t >> 4;

    __shared__ float4 sk[CH * CPAD];
    __shared__ float4 sv[CH * CPAD];
    __shared__ float  sn[4];

    // ---- stage K/V for entities t and t+256; accumulate mask sum ----
    float mw = 0.f;
    #pragma unroll
    for (int s = 0; s < 2; ++s) {
        const int e = t + s * 256;
        const float me = mask[b * NE + e];
        mw += me;
        const float2* rp = (const float2*)(inp + ((size_t)(b * NE + e)) * F);
        const float2 r0 = rp[0], r1 = rp[1], r2 = rp[2];
        const float x0 = r0.x * me, x1 = r0.y * me, x2 = r1.x * me,
                    x3 = r1.y * me, x4 = r2.x * me, x5 = r2.y * me;
        const float* wk = Wk + h * DPH * F;
        const float* wv = Wv + h * DPH * F;
        float kk[DPH], vv[DPH];
        #pragma unroll
        for (int d = 0; d < DPH; ++d) {
            const float* w = wk + d * F;
            kk[d] = x0*w[0] + x1*w[1] + x2*w[2] + x3*w[3] + x4*w[4] + x5*w[5];
            w = wv + d * F;
            vv[d] = x0*w[0] + x1*w[1] + x2*w[2] + x3*w[3] + x4*w[4] + x5*w[5];
        }
        sk[(e >> 5) * CPAD + (e & 31)] = make_float4(kk[0], kk[1], kk[2], kk[3]);
        sv[(e >> 5) * CPAD + (e & 31)] = make_float4(vv[0], vv[1], vv[2], vv[3]);
    }
    #pragma unroll
    for (int off = 32; off >= 1; off >>= 1) mw += __shfl_down(mw, off);
    if ((t & 63) == 0) sn[t >> 6] = mw;

    // ---- q for 8 rows as 4 packed pairs; fold 1/sqrt(4)*log2(e) ----
    const float QS = 0.5f * 1.44269504088896340736f;
    v2f qv[4][DPH];   // [pair][d] = {q_row2p[d], q_row2p+1[d]}
    {
        const float* wq = Wq + h * DPH * F;
        #pragma unroll
        for (int r = 0; r < 8; ++r) {
            const int row = quar * 128 + 8 * g + r;
            const float mr = mask[b * NE + row];
            const float2* rp = (const float2*)(inp + ((size_t)(b * NE + row)) * F);
            const float2 r0 = rp[0], r1 = rp[1], r2 = rp[2];
            const float x0 = r0.x * mr, x1 = r0.y * mr, x2 = r1.x * mr,
                        x3 = r1.y * mr, x4 = r2.x * mr, x5 = r2.y * mr;
            #pragma unroll
            for (int d = 0; d < DPH; ++d) {
                const float* w = wq + d * F;
                const float qd = QS * (x0*w[0] + x1*w[1] + x2*w[2] + x3*w[3] + x4*w[4] + x5*w[5]);
                if (r & 1) qv[r >> 1][d].y = qd; else qv[r >> 1][d].x = qd;
            }
        }
    }

    __syncthreads();

    const float Nb = sn[0] + sn[1] + sn[2] + sn[3];
    const float lcorr = 512.0f - Nb;      // exact: masked keys contribute e=1

    // ---- inner loop: 32 keys of chunk c × 4 row pairs (packed fp32) ----
    const float4* kb = sk + c * CPAD;
    const float4* vb = sv + c * CPAD;
    v2f l2[4], a2[4][DPH];
    #pragma unroll
    for (int p = 0; p < 4; ++p) {
        l2[p] = (v2f)(0.f);
        #pragma unroll
        for (int d = 0; d < DPH; ++d) a2[p][d] = (v2f)(0.f);
    }

    #pragma unroll 4
    for (int j = 0; j < CKEYS; ++j) {
        const float4 kv = kb[j];
        const float4 uv = vb[j];
        const v2f kx = (v2f){kv.x, kv.x}, ky = (v2f){kv.y, kv.y},
                  kz = (v2f){kv.z, kv.z}, kw = (v2f){kv.w, kv.w};
        const v2f ux = (v2f){uv.x, uv.x}, uy = (v2f){uv.y, uv.y},
                  uz = (v2f){uv.z, uv.z}, uw = (v2f){uv.w, uv.w};
        #pragma unroll
        for (int p = 0; p < 4; ++p) {
            v2f s = qv[p][3] * kw;
            s = __builtin_elementwise_fma(qv[p][2], kz, s);
            s = __builtin_elementwise_fma(qv[p][1], ky, s);
            s = __builtin_elementwise_fma(qv[p][0], kx, s);
            v2f e;
            e.x = EXP2(s.x);
            e.y = EXP2(s.y);
            l2[p] += e;
            a2[p][0] = __builtin_elementwise_fma(e, ux, a2[p][0]);
            a2[p][1] = __builtin_elementwise_fma(e, uy, a2[p][1]);
            a2[p][2] = __builtin_elementwise_fma(e, uz, a2[p][2]);
            a2[p][3] = __builtin_elementwise_fma(e, uw, a2[p][3]);
        }
    }

    // ---- butterfly over 16 lanes (combine 16 chunks) ----
    #pragma unroll
    for (int m = 1; m <= 8; m <<= 1) {
        #pragma unroll
        for (int p = 0; p < 4; ++p) {
            l2[p].x += __shfl_xor(l2[p].x, m);
            l2[p].y += __shfl_xor(l2[p].y, m);
            #pragma unroll
            for (int d = 0; d < DPH; ++d) {
                a2[p][d].x += __shfl_xor(a2[p][d].x, m);
                a2[p][d].y += __shfl_xor(a2[p][d].y, m);
            }
        }
    }

    // ---- lanes c<8 write row 8g + (c&7) (static unroll, no dyn indexing) ----
    const int rsel = c & 7;
    float lsel = l2[0].x, p0 = a2[0][0].x, p1 = a2[0][1].x,
          p2 = a2[0][2].x, p3 = a2[0][3].x;
    #pragma unroll
    for (int r = 1; r < 8; ++r) {
        if (r == rsel) {
            const int pp = r >> 1;
            if (r & 1) {
                lsel = l2[pp].y; p0 = a2[pp][0].y; p1 = a2[pp][1].y;
                p2 = a2[pp][2].y; p3 = a2[pp][3].y;
            } else {
                lsel = l2[pp].x; p0 = a2[pp][0].x; p1 = a2[pp][1].x;
                p2 = a2[pp][2].x; p3 = a2[pp][3].x;
            }
        }
    }

    if (c < 8) {
        const int row = quar * 128 + 8 * g + rsel;
        const float mi = mask[b * NE + row];
        const float rs = mi / (lsel - lcorr);   // masked rows: mi=0 -> 0
        float4* o = (float4*)(att_out + ((size_t)(b * NE + row)) * NEMBD + h * DPH);
        *o = make_float4(p0 * rs, p1 * rs, p2 * rs, p3 * rs);
    }
}

// ---------------------------------------------------------------------------
// epilogue: post-proj + residual + mask-corrected norm + masked mean pool.
// 128 blocks x 512 threads (verified correct rounds 1-4).
// ---------------------------------------------------------------------------
__global__ __launch_bounds__(NE) void epi_kernel(
    const float* __restrict__ inp, const float* __restrict__ mask,
    const float* __restrict__ Wpost, const float* __restrict__ att,
    float* __restrict__ out)
{
    const int b = blockIdx.x;
    const int i = threadIdx.x;
    const int wave = i >> 6;
    const int lane = i & 63;

    __shared__ float swp[F * NEMBD];
    __shared__ float red[64];

    if (i < F * NEMBD) swp[i] = Wpost[i];
    __syncthreads();

    const float mi = mask[b * NE + i];
    const float* row = inp + ((size_t)(b * NE + i)) * F;
    const float* ar  = att + ((size_t)(b * NE + i)) * NEMBD;

    float a[NEMBD];
    #pragma unroll
    for (int t = 0; t < NEMBD; t += 4) {
        const float4 v = *(const float4*)(ar + t);
        a[t] = v.x; a[t+1] = v.y; a[t+2] = v.z; a[t+3] = v.w;
    }

    float x[F];
    #pragma unroll
    for (int f = 0; f < F; ++f) {
        float acc = row[f] * mi;
        #pragma unroll
        for (int t = 0; t < NEMBD; ++t) acc = fmaf(a[t], swp[f * NEMBD + t], acc);
        x[f] = acc;
    }

    // ---- phase 1: S = sum(x), N = sum(mask) ----
    float rsum = x[0] + x[1] + x[2] + x[3] + x[4] + x[5];
    float rn = mi;
    #pragma unroll
    for (int off = 32; off >= 1; off >>= 1) {
        rsum += __shfl_down(rsum, off);
        rn   += __shfl_down(rn, off);
    }
    if (lane == 0) { red[wave * 2] = rsum; red[wave * 2 + 1] = rn; }
    __syncthreads();
    float S = 0.f, N = 0.f;
    #pragma unroll
    for (int w = 0; w < 8; ++w) { S += red[w * 2]; N += red[w * 2 + 1]; }

    const float mu     = S / (6.0f * N);
    const float sum_x2 = S + (NE - N) * 6.0f * mu;
    const float m2     = sum_x2 / (NE * 6.0f);
    const float add    = (1.0f - mi) * mu;

    float ss = 0.f;
    #pragma unroll
    for (int f = 0; f < F; ++f) { const float d = x[f] + add - m2; ss = fmaf(d, d, ss); }

    // ---- phase 2: sum of squares ----
    __syncthreads();
    #pragma unroll
    for (int off = 32; off >= 1; off >>= 1) ss += __shfl_down(ss, off);
    if (lane == 0) red[wave] = ss;
    __syncthreads();
    float vs = 0.f;
    #pragma unroll
    for (int w = 0; w < 8; ++w) vs += red[w];

    const float var  = vs / (NE * 6.0f - 1.0f);
    const float stdv = sqrtf(var) * sqrtf((6.0f * NE - 1.0f) / (6.0f * N - 1.0f));
    const float inv  = 1.0f / (stdv + 1e-6f);

    float y[F];
    #pragma unroll
    for (int f = 0; f < F; ++f) y[f] = mi * (x[f] - mu) * inv;

    // ---- phase 3: 6 masked feature sums ----
    __syncthreads();
    #pragma unroll
    for (int off = 32; off >= 1; off >>= 1) {
        #pragma unroll
        for (int f = 0; f < F; ++f) y[f] += __shfl_down(y[f], off);
    }
    if (lane == 0) {
        #pragma unroll
        for (int f = 0; f < F; ++f) red[wave * F + f] = y[f];
    }
    __syncthreads();
    if (i < F) {
        float tt = 0.f;
        #pragma unroll
        for (int w = 0; w < 8; ++w) tt += red[w * F + i];
        out[b * F + i] = tt / N;
    }
}

// ---------------------------------------------------------------------------
extern "C" void kernel_launch(void* const* d_in, const int* in_sizes, int n_in,
                              void* d_out, int out_size, void* d_ws, size_t ws_size,
                              hipStream_t stream) {
    const float* inp   = (const float*)d_in[0];
    const float* mask  = (const float*)d_in[1];
    const float* Wq    = (const float*)d_in[2];
    const float* Wk    = (const float*)d_in[3];
    const float* Wv    = (const float*)d_in[4];
    const float* Wpost = (const float*)d_in[5];
    float* out = (float*)d_out;
    float* att = (float*)d_ws;   // BS*NE*NEMBD floats = 4 MB

    attn_kernel<<<BS * NH * 4, 256, 0, stream>>>(inp, mask, Wq, Wk, Wv, att);
    epi_kernel <<<BS, NE, 0, stream>>>(inp, mask, Wpost, att, out);
}

// Round 6
// 95.453 us; speedup vs baseline: 1.1631x; 1.1631x over previous
//
#include <hip/hip_runtime.h>
#include <math.h>

#define BS    128
#define NE    512
#define F     6
#define NH    4
#define DPH   4
#define NEMBD 16

#define CH    8
#define CPAD  65   // float4 stride per chunk; 8 broadcast addrs/wave, conflict-free (measured r2-r5)

#if __has_builtin(__builtin_amdgcn_exp2f)
#define EXP2(x) __builtin_amdgcn_exp2f(x)
#else
#define EXP2(x) exp2f(x)
#endif

typedef float v2f __attribute__((ext_vector_type(2)));

// ---------------------------------------------------------------------------
// attention: 512 blocks = (b,h), 512 threads. Active-entity compaction:
// ballot/mbcnt/1-atomic-per-wave assigns compacted slots; slot s dealt
// round-robin to chunk s&7 at index s>>3, so the inner loop runs
// L = ceil(Nk/8) iterations (~52 for 80% density) instead of 64.
// Masked entities are skipped entirely (keys AND query rows); zero-padded
// tail slots contribute e=exp2(0)=1, removed exactly via lcorr = 8L - Nk.
// q computed once per row into LDS (was 8x redundant). No-max softmax
// (verified exact rounds 1-5). Butterfly over the c-octet combines chunks.
// ---------------------------------------------------------------------------
__global__ __launch_bounds__(512) void attn_kernel(
    const float* __restrict__ inp, const float* __restrict__ mask,
    const float* __restrict__ Wq, const float* __restrict__ Wk,
    const float* __restrict__ Wv, float* __restrict__ att_out)
{
    const int b    = blockIdx.x >> 2;
    const int h    = blockIdx.x & 3;
    const int t    = threadIdx.x;
    const int c    = t & 7;
    const int g    = t >> 3;
    const int w    = t >> 6;
    const int lane = t & 63;

    __shared__ float4 sk[CH * CPAD];
    __shared__ float4 sv[CH * CPAD];
    __shared__ float4 sq[576];            // row-slot s at sq[9*(s>>3) + (s&7)]
    __shared__ unsigned short rlist[512]; // compacted slot -> entity id
    __shared__ int scnt;
    __shared__ int swb[8];

    // ---- zero pass: thread t zeroes slot-position t in sk/sv/sq ----
    const float4 z4 = make_float4(0.f, 0.f, 0.f, 0.f);
    sk[c * CPAD + g] = z4;
    sv[c * CPAD + g] = z4;
    sq[9 * g + c]    = z4;
    if (t == 0) scnt = 0;

    const float me = mask[b * NE + t];
    const bool act = me > 0.f;            // mask is exactly 0.0 or 1.0

    __syncthreads();   // B1: zeros + counter init visible

    // ---- wave-aggregated compaction index ----
    const unsigned long long ball = __ballot(act);
    const unsigned int blo = (unsigned int)ball;
    const unsigned int bhi = (unsigned int)(ball >> 32);
    const int prefix = __builtin_amdgcn_mbcnt_hi(bhi,
                        __builtin_amdgcn_mbcnt_lo(blo, 0));
    if (lane == 0) swb[w] = atomicAdd(&scnt, (int)__popcll(ball));

    __syncthreads();   // B2: swb + final scnt visible

    const int Nk = scnt;                  // active entity count (= reference N)
    const int L  = (Nk + 7) >> 3;         // keys per chunk
    const float lcorr = (float)(8 * L - Nk);  // zero-pad slots contribute e=1

    // ---- staging: active thread computes K/V/Q for its entity -> slot s ----
    if (act) {
        const int s = swb[w] + prefix;
        const float2* rp = (const float2*)(inp + ((size_t)(b * NE + t)) * F);
        const float2 r0 = rp[0], r1 = rp[1], r2 = rp[2];
        const float x0 = r0.x, x1 = r0.y, x2 = r1.x,
                    x3 = r1.y, x4 = r2.x, x5 = r2.y;   // mask=1: no scaling
        const float* wk = Wk + h * DPH * F;
        const float* wv = Wv + h * DPH * F;
        const float* wq = Wq + h * DPH * F;
        const float QS = 0.5f * 1.44269504088896340736f;  // 1/sqrt(4)*log2(e)
        float kk[4], vv[4], qq[4];
        #pragma unroll
        for (int d = 0; d < DPH; ++d) {
            const float* wd = wk + d * F;
            kk[d] = x0*wd[0] + x1*wd[1] + x2*wd[2] + x3*wd[3] + x4*wd[4] + x5*wd[5];
            wd = wv + d * F;
            vv[d] = x0*wd[0] + x1*wd[1] + x2*wd[2] + x3*wd[3] + x4*wd[4] + x5*wd[5];
            wd = wq + d * F;
            qq[d] = QS * (x0*wd[0] + x1*wd[1] + x2*wd[2] + x3*wd[3] + x4*wd[4] + x5*wd[5]);
        }
        sk[(s & 7) * CPAD + (s >> 3)] = make_float4(kk[0], kk[1], kk[2], kk[3]);
        sv[(s & 7) * CPAD + (s >> 3)] = make_float4(vv[0], vv[1], vv[2], vv[3]);
        sq[9 * (s >> 3) + (s & 7)]    = make_float4(qq[0], qq[1], qq[2], qq[3]);
        rlist[s] = (unsigned short)t;
    }

    __syncthreads();   // B3: sk/sv/sq/rlist visible

    // ---- wave-granular row skip: wave w owns row-slots [64w, 64w+64) ----
    if (64 * w >= Nk) return;

    // ---- load q for row-slots 8g..8g+7 (8 broadcast b128, conflict-free) ----
    float4 qa[8];
    #pragma unroll
    for (int r = 0; r < 8; ++r) qa[r] = sq[9 * g + r];
    v2f qv[4][DPH];
    #pragma unroll
    for (int p = 0; p < 4; ++p) {
        qv[p][0] = (v2f){qa[2*p].x, qa[2*p+1].x};
        qv[p][1] = (v2f){qa[2*p].y, qa[2*p+1].y};
        qv[p][2] = (v2f){qa[2*p].z, qa[2*p+1].z};
        qv[p][3] = (v2f){qa[2*p].w, qa[2*p+1].w};
    }

    // ---- inner loop: L keys of chunk c x 4 packed row pairs ----
    const float4* kb = sk + c * CPAD;
    const float4* vb = sv + c * CPAD;
    v2f l2[4], a2[4][DPH];
    #pragma unroll
    for (int p = 0; p < 4; ++p) {
        l2[p] = (v2f)(0.f);
        #pragma unroll
        for (int d = 0; d < DPH; ++d) a2[p][d] = (v2f)(0.f);
    }

    #pragma unroll 4
    for (int j = 0; j < L; ++j) {
        const float4 kv = kb[j];
        const float4 uv = vb[j];
        const v2f kx = (v2f){kv.x, kv.x}, ky = (v2f){kv.y, kv.y},
                  kz = (v2f){kv.z, kv.z}, kw = (v2f){kv.w, kv.w};
        const v2f ux = (v2f){uv.x, uv.x}, uy = (v2f){uv.y, uv.y},
                  uz = (v2f){uv.z, uv.z}, uw = (v2f){uv.w, uv.w};
        #pragma unroll
        for (int p = 0; p < 4; ++p) {
            v2f s = qv[p][3] * kw;
            s = __builtin_elementwise_fma(qv[p][2], kz, s);
            s = __builtin_elementwise_fma(qv[p][1], ky, s);
            s = __builtin_elementwise_fma(qv[p][0], kx, s);
            v2f e;
            e.x = EXP2(s.x);
            e.y = EXP2(s.y);
            l2[p] += e;
            a2[p][0] = __builtin_elementwise_fma(e, ux, a2[p][0]);
            a2[p][1] = __builtin_elementwise_fma(e, uy, a2[p][1]);
            a2[p][2] = __builtin_elementwise_fma(e, uz, a2[p][2]);
            a2[p][3] = __builtin_elementwise_fma(e, uw, a2[p][3]);
        }
    }

    // ---- butterfly over the c-octet (combine 8 chunks) ----
    #pragma unroll
    for (int m = 1; m <= 4; m <<= 1) {
        #pragma unroll
        for (int p = 0; p < 4; ++p) {
            l2[p].x += __shfl_xor(l2[p].x, m);
            l2[p].y += __shfl_xor(l2[p].y, m);
            #pragma unroll
            for (int d = 0; d < DPH; ++d) {
                a2[p][d].x += __shfl_xor(a2[p][d].x, m);
                a2[p][d].y += __shfl_xor(a2[p][d].y, m);
            }
        }
    }

    // ---- lane selects row-slot 8g + c (static unroll) ----
    float lsel = l2[0].x, p0 = a2[0][0].x, p1 = a2[0][1].x,
          p2 = a2[0][2].x, p3 = a2[0][3].x;
    #pragma unroll
    for (int r = 1; r < 8; ++r) {
        if (r == c) {
            const int pp = r >> 1;
            if (r & 1) {
                lsel = l2[pp].y; p0 = a2[pp][0].y; p1 = a2[pp][1].y;
                p2 = a2[pp][2].y; p3 = a2[pp][3].y;
            } else {
                lsel = l2[pp].x; p0 = a2[pp][0].x; p1 = a2[pp][1].x;
                p2 = a2[pp][2].x; p3 = a2[pp][3].x;
            }
        }
    }

    const int slot = 8 * g + c;
    if (slot < Nk) {
        const int row = rlist[slot];       // active row: mask = 1
        const float rs = 1.0f / (lsel - lcorr);
        float4* o = (float4*)(att_out + ((size_t)(b * NE + row)) * NEMBD + h * DPH);
        *o = make_float4(p0 * rs, p1 * rs, p2 * rs, p3 * rs);
    }
}

// ---------------------------------------------------------------------------
// epilogue: post-proj + residual + mask-corrected norm + masked mean pool.
// att rows of masked entities are never written (poison) -> zeroed via *mi.
// ---------------------------------------------------------------------------
__global__ __launch_bounds__(NE) void epi_kernel(
    const float* __restrict__ inp, const float* __restrict__ mask,
    const float* __restrict__ Wpost, const float* __restrict__ att,
    float* __restrict__ out)
{
    const int b = blockIdx.x;
    const int i = threadIdx.x;
    const int wave = i >> 6;
    const int lane = i & 63;

    __shared__ float swp[F * NEMBD];
    __shared__ float red[64];

    if (i < F * NEMBD) swp[i] = Wpost[i];
    __syncthreads();

    const float mi = mask[b * NE + i];
    const float* row = inp + ((size_t)(b * NE + i)) * F;
    const float* ar  = att + ((size_t)(b * NE + i)) * NEMBD;

    float a[NEMBD];
    #pragma unroll
    for (int t = 0; t < NEMBD; t += 4) {
        const float4 v = *(const float4*)(ar + t);
        a[t] = v.x * mi; a[t+1] = v.y * mi; a[t+2] = v.z * mi; a[t+3] = v.w * mi;
    }

    float x[F];
    #pragma unroll
    for (int f = 0; f < F; ++f) {
        float acc = row[f] * mi;
        #pragma unroll
        for (int t = 0; t < NEMBD; ++t) acc = fmaf(a[t], swp[f * NEMBD + t], acc);
        x[f] = acc;
    }

    // ---- phase 1: S = sum(x), N = sum(mask) ----
    float rsum = x[0] + x[1] + x[2] + x[3] + x[4] + x[5];
    float rn = mi;
    #pragma unroll
    for (int off = 32; off >= 1; off >>= 1) {
        rsum += __shfl_down(rsum, off);
        rn   += __shfl_down(rn, off);
    }
    if (lane == 0) { red[wave * 2] = rsum; red[wave * 2 + 1] = rn; }
    __syncthreads();
    float S = 0.f, N = 0.f;
    #pragma unroll
    for (int w = 0; w < 8; ++w) { S += red[w * 2]; N += red[w * 2 + 1]; }

    const float mu     = S / (6.0f * N);
    const float sum_x2 = S + (NE - N) * 6.0f * mu;
    const float m2     = sum_x2 / (NE * 6.0f);
    const float add    = (1.0f - mi) * mu;

    float ss = 0.f;
    #pragma unroll
    for (int f = 0; f < F; ++f) { const float d = x[f] + add - m2; ss = fmaf(d, d, ss); }

    // ---- phase 2: sum of squares ----
    __syncthreads();
    #pragma unroll
    for (int off = 32; off >= 1; off >>= 1) ss += __shfl_down(ss, off);
    if (lane == 0) red[wave] = ss;
    __syncthreads();
    float vs = 0.f;
    #pragma unroll
    for (int w = 0; w < 8; ++w) vs += red[w];

    const float var  = vs / (NE * 6.0f - 1.0f);
    const float stdv = sqrtf(var) * sqrtf((6.0f * NE - 1.0f) / (6.0f * N - 1.0f));
    const float inv  = 1.0f / (stdv + 1e-6f);

    float y[F];
    #pragma unroll
    for (int f = 0; f < F; ++f) y[f] = mi * (x[f] - mu) * inv;

    // ---- phase 3: 6 masked feature sums ----
    __syncthreads();
    #pragma unroll
    for (int off = 32; off >= 1; off >>= 1) {
        #pragma unroll
        for (int f = 0; f < F; ++f) y[f] += __shfl_down(y[f], off);
    }
    if (lane == 0) {
        #pragma unroll
        for (int f = 0; f < F; ++f) red[wave * F + f] = y[f];
    }
    __syncthreads();
    if (i < F) {
        float tt = 0.f;
        #pragma unroll
        for (int w = 0; w < 8; ++w) tt += red[w * F + i];
        out[b * F + i] = tt / N;
    }
}

// ---------------------------------------------------------------------------
extern "C" void kernel_launch(void* const* d_in, const int* in_sizes, int n_in,
                              void* d_out, int out_size, void* d_ws, size_t ws_size,
                              hipStream_t stream) {
    const float* inp   = (const float*)d_in[0];
    const float* mask  = (const float*)d_in[1];
    const float* Wq    = (const float*)d_in[2];
    const float* Wk    = (const float*)d_in[3];
    const float* Wv    = (const float*)d_in[4];
    const float* Wpost = (const float*)d_in[5];
    float* out = (float*)d_out;
    float* att = (float*)d_ws;   // BS*NE*NEMBD floats = 4 MB

    attn_kernel<<<BS * NH, 512, 0, stream>>>(inp, mask, Wq, Wk, Wv, att);
    epi_kernel <<<BS, NE, 0, stream>>>(inp, mask, Wpost, att, out);
}